// Round 20
// baseline (295.990 us; speedup 1.0000x reference)
//
#include <hip/hip_runtime.h>

// SimSiam: N=8192, D=256, H=128, fp32 in/out.
// Sim via split-fp32 bf16 MFMA: sim = Ah·Bh^T + Al·Bh^T + Ah·Bl^T.
// R20 = R19 with BK=64 rounds: stage TWO K-tiles of Ah/Bh per round (32KB
// slot, 8 gloads/wave), process both between one barrier pair -> barrier
// pairs 8->4, stage latency covered by 2x compute. al/bl still direct
// L2->VGPR with late placement (12 live frags max, no spill). 128x128 tile,
// 4 waves (2x2 of 64x64), 4 independent blocks/CU, both sims merged.
// Planes in MFMA-tile format:
//   granule16B(panel,kt,kq,m) = ((panel*8+kt)*4+kq)*128+m   (panel = 128 rows)
// 2D XCD swizzle (16 rowTiles x 32 colTiles per XCD).
// Loss = mean(diag(sim)) from diagonal blocks' accumulators.

static constexpr int N = 8192;
static constexpr int D = 256;
static constexpr int H = 128;

typedef __attribute__((ext_vector_type(8))) short s16x8;
typedef __attribute__((ext_vector_type(4))) float fp32x4;
typedef unsigned long long ull;

__device__ __forceinline__ unsigned f2ord(float f) {
    unsigned u = __float_as_uint(f);
    return (u & 0x80000000u) ? ~u : (u | 0x80000000u);
}
__device__ __forceinline__ ull umax64(ull a, ull b) { return a > b ? a : b; }
__device__ __forceinline__ unsigned short bf16_rtne(float f) {
    unsigned u = __float_as_uint(f);
    unsigned r = 0x7FFFu + ((u >> 16) & 1u);
    return (unsigned short)((u + r) >> 16);
}
__device__ __forceinline__ float bf_f(unsigned short h) {
    return __uint_as_float((unsigned)h << 16);
}
__device__ __forceinline__ void split_store(float f, unsigned short* h, unsigned short* l) {
    unsigned short hb = bf16_rtne(f);
    *h = hb;
    *l = bf16_rtne(f - bf_f(hb));
}
__device__ __forceinline__ void gload16(const unsigned short* g, void* lds) {
    __builtin_amdgcn_global_load_lds(
        (const __attribute__((address_space(1))) unsigned int*)g,
        (__attribute__((address_space(3))) unsigned int*)lds, 16, 0, 0);
}
// tile-format granule index (in ushort units)
__device__ __forceinline__ size_t gidx(int panel, int kt, int kq, int m) {
    return (((size_t)(panel * 8 + kt) * 4 + kq) * 128 + m) * 8;
}

// ---------------------------------------------------------------------------
// Kernel 1 (fused prep):
//   blocks [0,512):   MLP+rownorm -> tile-format hi/lo planes (x then y)
//   blocks [512,768): key/cnt/diag zeroing + plain rownorm of x,y
// ---------------------------------------------------------------------------
static constexpr int MLP_ROWS = 32;

__global__ __launch_bounds__(256) void prep_kernel(
    const float* __restrict__ x, const float* __restrict__ y,
    const float* __restrict__ W1, const float* __restrict__ b1,
    const float* __restrict__ W2, const float* __restrict__ b2,
    unsigned short* __restrict__ pxh, unsigned short* __restrict__ pxl,
    unsigned short* __restrict__ pyh, unsigned short* __restrict__ pyl,
    unsigned short* __restrict__ xh, unsigned short* __restrict__ xl,
    unsigned short* __restrict__ yh, unsigned short* __restrict__ yl,
    ull* __restrict__ keys, int* __restrict__ cnt, float* __restrict__ diagParts)
{
    const int bid = blockIdx.x;
    const int t = threadIdx.x;

    if (bid < 512) {
        // ---------------- MLP branch ----------------
        __shared__ float sV[MLP_ROWS][D + 4];
        __shared__ float sH[MLP_ROWS][H + 4];
        __shared__ float sNrm[MLP_ROWS];

        const float* V = (bid < 256) ? x : y;
        unsigned short* Ph = (bid < 256) ? pxh : pyh;
        unsigned short* Pl = (bid < 256) ? pxl : pyl;
        const int rowBase = (bid & 255) * MLP_ROWS;

        for (int i = t; i < MLP_ROWS * (D / 4); i += 256) {
            int r = i >> 6, c4 = i & 63;
            float4 v = *reinterpret_cast<const float4*>(&V[(size_t)(rowBase + r) * D + c4 * 4]);
            sV[r][c4 * 4 + 0] = v.x; sV[r][c4 * 4 + 1] = v.y;
            sV[r][c4 * 4 + 2] = v.z; sV[r][c4 * 4 + 3] = v.w;
        }
        __syncthreads();

        {   // H = relu(V@W1 + b1)
            const int c = t & (H - 1);
            const int r0 = (t >> 7) * 16;
            float acc[16];
#pragma unroll
            for (int i = 0; i < 16; ++i) acc[i] = 0.f;
            for (int k4 = 0; k4 < D / 4; ++k4) {
                float w0 = W1[(k4 * 4 + 0) * H + c];
                float w1 = W1[(k4 * 4 + 1) * H + c];
                float w2 = W1[(k4 * 4 + 2) * H + c];
                float w3 = W1[(k4 * 4 + 3) * H + c];
#pragma unroll
                for (int i = 0; i < 16; ++i) {
                    float4 v = *reinterpret_cast<const float4*>(&sV[r0 + i][k4 * 4]);
                    acc[i] = fmaf(v.w, w3, fmaf(v.z, w2, fmaf(v.y, w1, fmaf(v.x, w0, acc[i]))));
                }
            }
            float bb = b1[c];
#pragma unroll
            for (int i = 0; i < 16; ++i) {
                float h = acc[i] + bb;
                sH[r0 + i][c] = h > 0.f ? h : 0.f;
            }
        }
        __syncthreads();

        {   // P = H@W2 + b2 -> back into sV
            const int c = t;
            float acc[MLP_ROWS];
#pragma unroll
            for (int i = 0; i < MLP_ROWS; ++i) acc[i] = 0.f;
            for (int k4 = 0; k4 < H / 4; ++k4) {
                float w0 = W2[(k4 * 4 + 0) * D + c];
                float w1 = W2[(k4 * 4 + 1) * D + c];
                float w2 = W2[(k4 * 4 + 2) * D + c];
                float w3 = W2[(k4 * 4 + 3) * D + c];
#pragma unroll
                for (int i = 0; i < MLP_ROWS; ++i) {
                    float4 v = *reinterpret_cast<const float4*>(&sH[i][k4 * 4]);
                    acc[i] = fmaf(v.w, w3, fmaf(v.z, w2, fmaf(v.y, w1, fmaf(v.x, w0, acc[i]))));
                }
            }
            float bb = b2[c];
            __syncthreads();
#pragma unroll
            for (int i = 0; i < MLP_ROWS; ++i) sV[i][c] = acc[i] + bb;
        }
        __syncthreads();

        {   // row norms
            const int wave = t >> 6, lane = t & 63;
            for (int r = wave; r < MLP_ROWS; r += 4) {
                float s = 0.f;
#pragma unroll
                for (int c = 0; c < D / 64; ++c) {
                    float v = sV[r][lane + c * 64];
                    s = fmaf(v, v, s);
                }
#pragma unroll
                for (int off = 32; off > 0; off >>= 1) s += __shfl_down(s, off);
                if (lane == 0) sNrm[r] = s;
            }
        }
        __syncthreads();

        for (int i = t; i < MLP_ROWS * (D / 4); i += 256) {
            int r = i >> 6, c4 = i & 63;
            float scale = 1.0f / fmaxf(sqrtf(sNrm[r]), 1e-12f);
            ushort4 h, l;
            split_store(sV[r][c4 * 4 + 0] * scale, &h.x, &l.x);
            split_store(sV[r][c4 * 4 + 1] * scale, &h.y, &l.y);
            split_store(sV[r][c4 * 4 + 2] * scale, &h.z, &l.z);
            split_store(sV[r][c4 * 4 + 3] * scale, &h.w, &l.w);
            int grow = rowBase + r;
            size_t g = gidx(grow >> 7, c4 >> 3, (c4 >> 1) & 3, grow & 127) + (size_t)(c4 & 1) * 4;
            *reinterpret_cast<ushort4*>(&Ph[g]) = h;
            *reinterpret_cast<ushort4*>(&Pl[g]) = l;
        }
    } else {
        // ---------------- rownorm + zeroing branch ----------------
        const int rb = bid - 512;               // 0..255
        if (t < 128) keys[rb * 128 + t] = 0ULL; // zero 32768 keys total
        if (bid == 512) {
            if (t < 128) diagParts[t] = 0.f;
            if (t < 4) cnt[t] = 0;
        }
        const int wave = t >> 6, lane = t & 63;
#pragma unroll 1
        for (int i = 0; i < 16; ++i) {
            int gr = rb * 64 + wave * 16 + i;    // 0..16383
            const float* V = (gr < N) ? x : y;
            unsigned short* Vh = (gr < N) ? xh : yh;
            unsigned short* Vl = (gr < N) ? xl : yl;
            int row = gr & (N - 1);
            float4 v = *reinterpret_cast<const float4*>(&V[(size_t)row * D + lane * 4]);
            float s = fmaf(v.x, v.x, fmaf(v.y, v.y, fmaf(v.z, v.z, v.w * v.w)));
#pragma unroll
            for (int off = 32; off > 0; off >>= 1) s += __shfl_down(s, off);
            s = __shfl(s, 0);
            float scale = 1.0f / fmaxf(sqrtf(s), 1e-12f);
            ushort4 h, l;
            split_store(v.x * scale, &h.x, &l.x);
            split_store(v.y * scale, &h.y, &l.y);
            split_store(v.z * scale, &h.z, &l.z);
            split_store(v.w * scale, &h.w, &l.w);
            size_t g = gidx(row >> 7, lane >> 3, (lane >> 1) & 3, row & 127) + (size_t)(lane & 1) * 4;
            *reinterpret_cast<ushort4*>(&Vh[g]) = h;
            *reinterpret_cast<ushort4*>(&Vl[g]) = l;
        }
    }
}

// ---------------------------------------------------------------------------
// Kernel 2: both sims in one 8192-block launch (bit 12 selects sim_x/sim_y).
// Per sim: 128x128 tile, 4 waves (2x2 of 64x64). Per ROUND (2 K-tiles):
// stage Ah/Bh of both tiles to LDS (32KB slot, 8 gloads/wave); per sub-tile
// al issued early (arrives under hh), bl fenced below lh. Barrier pairs 4.
// ---------------------------------------------------------------------------
__global__ __launch_bounds__(256, 4) void sim_argmax_mfma(
    const unsigned short* __restrict__ Axh, const unsigned short* __restrict__ Axl,
    const unsigned short* __restrict__ Byh, const unsigned short* __restrict__ Byl,
    const unsigned short* __restrict__ Ayh, const unsigned short* __restrict__ Ayl,
    const unsigned short* __restrict__ Bxh, const unsigned short* __restrict__ Bxl,
    ull* __restrict__ keys, float* __restrict__ diagParts)
{
    __shared__ s16x8 sS[4][512];      // 32 KB: [ktpar*2 + {Ah,Bh}][kq*128+m]
    __shared__ ull kbufR[128][2];     // 2 KB
    __shared__ ull kbufC[128][2];     // 2 KB
    __shared__ float sDiag[4];

    const int t = threadIdx.x;
    const int w = t >> 6, lane = t & 63;
    const int wr = w >> 1, wc = w & 1;   // 2x2 wave grid, each 64x64

    const int bidFull = blockIdx.x;
    const int sim = bidFull >> 12;                    // 0: pxn@yn^T, 1: pyn@xn^T
    const int bid = bidFull & 4095;

    const unsigned short* Ah = sim ? Ayh : Axh;
    const unsigned short* Al = sim ? Ayl : Axl;
    const unsigned short* Bh = sim ? Bxh : Byh;
    const unsigned short* Bl = sim ? Bxl : Byl;
    ull* rowKeys = keys + (sim ? 2 * N : 0);
    ull* colKeys = keys + (sim ? 3 * N : (size_t)N);
    float* diagP = diagParts + (sim ? 64 : 0);

    // 2D XCD swizzle: 4096 tiles/sim = 64x64; XCD k owns
    // rowTiles [(k&3)*16,+16) x colTiles [(k>>2)*32,+32); row fastest.
    const int xcd = bid & 7, local = bid >> 3;        // local 0..511
    const int rowTile = (xcd & 3) * 16 + (local & 15);
    const int colTile = (xcd >> 2) * 32 + (local >> 4);
    const int rowBase = rowTile * 128;
    const int colBase = colTile * 128;

    fp32x4 acc[4][4];
#pragma unroll
    for (int i = 0; i < 4; ++i)
#pragma unroll
        for (int j = 0; j < 4; ++j) acc[i][j] = (fp32x4){0.f, 0.f, 0.f, 0.f};

    // per-plane granule bases for this block (ushort units)
    const unsigned short* pAh = Ah + (size_t)rowTile * 4096 * 8;
    const unsigned short* pBh = Bh + (size_t)colTile * 4096 * 8;

    // direct-load per-wave fragment bases for the low planes
    const int fOff = (lane >> 4) * 128 + (lane & 15);
    const unsigned short* aL = Al + ((size_t)rowTile * 4096 + fOff + wr * 64) * 8;
    const unsigned short* bL = Bl + ((size_t)colTile * 4096 + fOff + wc * 64) * 8;

#define FRAG(base, kt, f) (*reinterpret_cast<const s16x8*>((base) + ((size_t)(kt) * 512 + (f) * 16) * 8))

    // stage ROUND r (K-tiles 2r, 2r+1): 8 x 1KB gload16 per wave.
#define STAGE(r)                                                                \
    do {                                                                        \
        const size_t o0 = (size_t)(2 * (r)) * 512 + w * 128 + lane;             \
        const size_t o1 = o0 + 64;                                              \
        const size_t o2 = o0 + 512;                                             \
        const size_t o3 = o0 + 576;                                             \
        gload16(pAh + o0 * 8, (void*)&sS[0][w * 128]);                          \
        gload16(pAh + o1 * 8, (void*)&sS[0][w * 128 + 64]);                     \
        gload16(pBh + o0 * 8, (void*)&sS[1][w * 128]);                          \
        gload16(pBh + o1 * 8, (void*)&sS[1][w * 128 + 64]);                     \
        gload16(pAh + o2 * 8, (void*)&sS[2][w * 128]);                          \
        gload16(pAh + o3 * 8, (void*)&sS[2][w * 128 + 64]);                     \
        gload16(pBh + o2 * 8, (void*)&sS[3][w * 128]);                          \
        gload16(pBh + o3 * 8, (void*)&sS[3][w * 128 + 64]);                     \
    } while (0)

    STAGE(0);

    const int aBase = fOff + wr * 64;
    const int bBase = fOff + wc * 64;

#pragma unroll 1
    for (int r = 0; r < 4; ++r) {
        __syncthreads();   // syncA: STAGE(r) landed for all waves (vmcnt(0))

#pragma unroll
        for (int j = 0; j < 2; ++j) {
            const int kt = 2 * r + j;

            // issue al early: arrives under the hh cluster (consumed in lh)
            s16x8 al[4];
#pragma unroll
            for (int f = 0; f < 4; ++f) al[f] = FRAG(aL, kt, f);

            s16x8 ah[4], bh[4];
#pragma unroll
            for (int f = 0; f < 4; ++f) ah[f] = sS[2 * j + 0][aBase + f * 16];
#pragma unroll
            for (int f = 0; f < 4; ++f) bh[f] = sS[2 * j + 1][bBase + f * 16];

            __builtin_amdgcn_s_setprio(1);
#pragma unroll
            for (int fm = 0; fm < 4; ++fm)
#pragma unroll
                for (int fn = 0; fn < 4; ++fn)
                    acc[fm][fn] = __builtin_amdgcn_mfma_f32_16x16x32_bf16(ah[fm], bh[fn], acc[fm][fn], 0, 0, 0);
            __builtin_amdgcn_s_setprio(0);

            __builtin_amdgcn_s_setprio(1);
#pragma unroll
            for (int fm = 0; fm < 4; ++fm)
#pragma unroll
                for (int fn = 0; fn < 4; ++fn)
                    acc[fm][fn] = __builtin_amdgcn_mfma_f32_16x16x32_bf16(al[fm], bh[fn], acc[fm][fn], 0, 0, 0);
            __builtin_amdgcn_s_setprio(0);

            // fence: keep bl loads BELOW lh so peak liveness stays at 12 frags
            __builtin_amdgcn_sched_barrier(0);

            {   // high-A x low-B: bl fetched direct; stall cross-block hidden
                s16x8 bl[4];
#pragma unroll
                for (int f = 0; f < 4; ++f) bl[f] = FRAG(bL, kt, f);
                __builtin_amdgcn_s_setprio(1);
#pragma unroll
                for (int fm = 0; fm < 4; ++fm)
#pragma unroll
                    for (int fn = 0; fn < 4; ++fn)
                        acc[fm][fn] = __builtin_amdgcn_mfma_f32_16x16x32_bf16(ah[fm], bl[fn], acc[fm][fn], 0, 0, 0);
                __builtin_amdgcn_s_setprio(0);
            }
        }

        __syncthreads();               // syncB: all waves done reading the slot
        if (r < 3) STAGE(r + 1);       // overwrite; next syncA waits it
    }
#undef STAGE
#undef FRAG

    const int R0 = wr * 64;
    const int C0 = wc * 64;

    // ---- diagonal (loss) partial ----
    if (rowTile == colTile) {
        float s = 0.f;
        if (wr == wc) {
            int dr = (lane & 15) - (lane >> 4) * 4;
            if (dr >= 0 && dr < 4) {
#pragma unroll
                for (int fm = 0; fm < 4; ++fm) s += acc[fm][fm][dr];
            }
        }
#pragma unroll
        for (int off = 32; off > 0; off >>= 1) s += __shfl_down(s, off);
        if (lane == 0) sDiag[w] = s;
        __syncthreads();
        if (t == 0) diagP[rowTile] = ((sDiag[0] + sDiag[1]) + sDiag[2]) + sDiag[3];
    }

    // ---- row argmax candidates (value-first); C/D: col=lane&15, row=(lane>>4)*4+r
#pragma unroll
    for (int fm = 0; fm < 4; ++fm) {
#pragma unroll
        for (int r = 0; r < 4; ++r) {
            int rowLoc = R0 + fm * 16 + (lane >> 4) * 4 + r;
            float m = fmaxf(fmaxf(acc[fm][0][r], acc[fm][1][r]), fmaxf(acc[fm][2][r], acc[fm][3][r]));
#pragma unroll
            for (int off = 1; off < 16; off <<= 1) m = fmaxf(m, __shfl_xor(m, off));
            unsigned idx = 0xFFFFFFFFu;
#pragma unroll
            for (int fn = 0; fn < 4; ++fn) {
                unsigned gcol = (unsigned)(colBase + C0 + fn * 16 + (lane & 15));
                if (acc[fm][fn][r] == m && gcol < idx) idx = gcol;
            }
#pragma unroll
            for (int off = 1; off < 16; off <<= 1) {
                unsigned o = __shfl_xor(idx, off);
                if (o < idx) idx = o;
            }
            if ((lane & 15) == 0)
                kbufR[rowLoc][wc] = ((ull)f2ord(m) << 32) | (unsigned)(~idx);
        }
    }

    // ---- col argmax candidates ----
#pragma unroll
    for (int fn = 0; fn < 4; ++fn) {
        int colLoc = C0 + fn * 16 + (lane & 15);
        float m = -3.4e38f;
#pragma unroll
        for (int fm = 0; fm < 4; ++fm) {
            float m01 = fmaxf(acc[fm][fn][0], acc[fm][fn][1]);
            float m23 = fmaxf(acc[fm][fn][2], acc[fm][fn][3]);
            m = fmaxf(m, fmaxf(m01, m23));
        }
        m = fmaxf(m, __shfl_xor(m, 16));
        m = fmaxf(m, __shfl_xor(m, 32));
        unsigned idx = 0xFFFFFFFFu;
#pragma unroll
        for (int fm = 0; fm < 4; ++fm) {
#pragma unroll
            for (int r = 0; r < 4; ++r) {
                unsigned grow = (unsigned)(rowBase + R0 + fm * 16 + (lane >> 4) * 4 + r);
                if (acc[fm][fn][r] == m && grow < idx) idx = grow;
            }
        }
        {
            unsigned o = __shfl_xor(idx, 16);
            if (o < idx) idx = o;
            o = __shfl_xor(idx, 32);
            if (o < idx) idx = o;
        }
        if ((lane >> 4) == 0)
            kbufC[colLoc][wr] = ((ull)f2ord(m) << 32) | (unsigned)(~idx);
    }

    __syncthreads();

    // ---- one global atomic per row / col ----
    if (t < 128) {
        ull best = umax64(kbufR[t][0], kbufR[t][1]);
        atomicMax(&rowKeys[rowBase + t], best);
    } else {
        int c = t - 128;
        ull best = umax64(kbufC[c][0], kbufC[c][1]);
        atomicMax(&colKeys[colBase + c], best);
    }
}

// ---------------------------------------------------------------------------
// Kernel 3: parallel deterministic counts (int atomics).
// ---------------------------------------------------------------------------
__global__ __launch_bounds__(256) void count_kernel(const ull* __restrict__ keys, int* __restrict__ cnt)
{
    const int t = threadIdx.x;
    const int i = blockIdx.x * 256 + t;
    const int lane = t & 63;
#pragma unroll
    for (int a = 0; a < 4; ++a) {
        int s = ((~(unsigned)keys[a * N + i]) == (unsigned)i);
#pragma unroll
        for (int off = 32; off > 0; off >>= 1) s += __shfl_down(s, off);
        if (lane == 0) atomicAdd(&cnt[a], s);
    }
}

// ---------------------------------------------------------------------------
// Kernel 4: final scalars.
// ---------------------------------------------------------------------------
__global__ __launch_bounds__(64) void final_kernel(
    const float* __restrict__ diagParts, const int* __restrict__ cnt, float* __restrict__ out)
{
    const int lane = threadIdx.x;
    double vx = (double)diagParts[lane];
    double vy = (double)diagParts[64 + lane];
#pragma unroll
    for (int off = 32; off > 0; off >>= 1) {
        vx += __shfl_down(vx, off);
        vy += __shfl_down(vy, off);
    }
    if (lane == 0) {
        float invN = 1.0f / (float)N;
        out[0] = (float)(-0.5 * (vx + vy) / (double)N);
        out[1] = 0.5f * ((float)cnt[1] * invN) + (float)cnt[0] * invN;
        out[2] = 0.5f * ((float)cnt[3] * invN) + (float)cnt[2] * invN;
    }
}

// ---------------------------------------------------------------------------
extern "C" void kernel_launch(void* const* d_in, const int* in_sizes, int n_in,
                              void* d_out, int out_size, void* d_ws, size_t ws_size,
                              hipStream_t stream)
{
    (void)in_sizes; (void)n_in; (void)out_size; (void)ws_size;
    const float* x  = (const float*)d_in[0];
    const float* y  = (const float*)d_in[1];
    const float* W1 = (const float*)d_in[2];
    const float* b1 = (const float*)d_in[3];
    const float* W2 = (const float*)d_in[4];
    const float* b2 = (const float*)d_in[5];
    float* out = (float*)d_out;

    const size_t ND = (size_t)N * D;
    unsigned short* pxh = (unsigned short*)d_ws;   // 8 bf16 planes x 4 MB = 32 MB
    unsigned short* pxl = pxh + ND;
    unsigned short* pyh = pxl + ND;
    unsigned short* pyl = pyh + ND;
    unsigned short* xh  = pyl + ND;
    unsigned short* xl  = xh + ND;
    unsigned short* yh  = xl + ND;
    unsigned short* yl  = yh + ND;
    ull* keys = (ull*)(yl + ND);                   // 256 KB
    float* diagParts = (float*)(keys + 4 * N);     // 128 floats
    int* cnt = (int*)(diagParts + 128);            // 4 ints

    prep_kernel<<<768, 256, 0, stream>>>(x, y, W1, b1, W2, b2,
                                         pxh, pxl, pyh, pyl, xh, xl, yh, yl,
                                         keys, cnt, diagParts);

    sim_argmax_mfma<<<8192, 256, 0, stream>>>(pxh, pxl, yh, yl,
                                              pyh, pyl, xh, xl,
                                              keys, diagParts);

    count_kernel<<<32, 256, 0, stream>>>(keys, cnt);
    final_kernel<<<1, 64, 0, stream>>>(diagParts, cnt, out);
}

// Round 21
// 275.695 us; speedup vs baseline: 1.0736x; 1.0736x over previous
//
#include <hip/hip_runtime.h>

// SimSiam: N=8192, D=256, H=128, fp32 in/out.
// Sim via split-fp32 bf16 MFMA: sim = Ah·Bh^T + Al·Bh^T + Ah·Bl^T.
// R21 = R19 verbatim (best measured: 276 us; R20's BK=64 double-tile round
// re-triggered the spill mode, WRITE 65->163 MB). Ah/Bh staged via LDS
// (shared), al/bl fetched direct L2->VGPR with LATE placement (al at loop
// top under hh, bl fenced below lh) -> peak 12 live fragments, no spill.
// 128x128 tile, 4 waves (2x2 of 64x64), m97-style 2-barrier loop,
// 4 independent blocks/CU, both sims merged in one 8192-block launch.
// Planes in MFMA-tile format:
//   granule16B(panel,kt,kq,m) = ((panel*8+kt)*4+kq)*128+m   (panel = 128 rows)
// 2D XCD swizzle (16 rowTiles x 32 colTiles per XCD).
// Loss = mean(diag(sim)) from diagonal blocks' accumulators.

static constexpr int N = 8192;
static constexpr int D = 256;
static constexpr int H = 128;

typedef __attribute__((ext_vector_type(8))) short s16x8;
typedef __attribute__((ext_vector_type(4))) float fp32x4;
typedef unsigned long long ull;

__device__ __forceinline__ unsigned f2ord(float f) {
    unsigned u = __float_as_uint(f);
    return (u & 0x80000000u) ? ~u : (u | 0x80000000u);
}
__device__ __forceinline__ ull umax64(ull a, ull b) { return a > b ? a : b; }
__device__ __forceinline__ unsigned short bf16_rtne(float f) {
    unsigned u = __float_as_uint(f);
    unsigned r = 0x7FFFu + ((u >> 16) & 1u);
    return (unsigned short)((u + r) >> 16);
}
__device__ __forceinline__ float bf_f(unsigned short h) {
    return __uint_as_float((unsigned)h << 16);
}
__device__ __forceinline__ void split_store(float f, unsigned short* h, unsigned short* l) {
    unsigned short hb = bf16_rtne(f);
    *h = hb;
    *l = bf16_rtne(f - bf_f(hb));
}
__device__ __forceinline__ void gload16(const unsigned short* g, void* lds) {
    __builtin_amdgcn_global_load_lds(
        (const __attribute__((address_space(1))) unsigned int*)g,
        (__attribute__((address_space(3))) unsigned int*)lds, 16, 0, 0);
}
// tile-format granule index (in ushort units)
__device__ __forceinline__ size_t gidx(int panel, int kt, int kq, int m) {
    return (((size_t)(panel * 8 + kt) * 4 + kq) * 128 + m) * 8;
}

// ---------------------------------------------------------------------------
// Kernel 1 (fused prep):
//   blocks [0,512):   MLP+rownorm -> tile-format hi/lo planes (x then y)
//   blocks [512,768): key/cnt/diag zeroing + plain rownorm of x,y
// ---------------------------------------------------------------------------
static constexpr int MLP_ROWS = 32;

__global__ __launch_bounds__(256) void prep_kernel(
    const float* __restrict__ x, const float* __restrict__ y,
    const float* __restrict__ W1, const float* __restrict__ b1,
    const float* __restrict__ W2, const float* __restrict__ b2,
    unsigned short* __restrict__ pxh, unsigned short* __restrict__ pxl,
    unsigned short* __restrict__ pyh, unsigned short* __restrict__ pyl,
    unsigned short* __restrict__ xh, unsigned short* __restrict__ xl,
    unsigned short* __restrict__ yh, unsigned short* __restrict__ yl,
    ull* __restrict__ keys, int* __restrict__ cnt, float* __restrict__ diagParts)
{
    const int bid = blockIdx.x;
    const int t = threadIdx.x;

    if (bid < 512) {
        // ---------------- MLP branch ----------------
        __shared__ float sV[MLP_ROWS][D + 4];
        __shared__ float sH[MLP_ROWS][H + 4];
        __shared__ float sNrm[MLP_ROWS];

        const float* V = (bid < 256) ? x : y;
        unsigned short* Ph = (bid < 256) ? pxh : pyh;
        unsigned short* Pl = (bid < 256) ? pxl : pyl;
        const int rowBase = (bid & 255) * MLP_ROWS;

        for (int i = t; i < MLP_ROWS * (D / 4); i += 256) {
            int r = i >> 6, c4 = i & 63;
            float4 v = *reinterpret_cast<const float4*>(&V[(size_t)(rowBase + r) * D + c4 * 4]);
            sV[r][c4 * 4 + 0] = v.x; sV[r][c4 * 4 + 1] = v.y;
            sV[r][c4 * 4 + 2] = v.z; sV[r][c4 * 4 + 3] = v.w;
        }
        __syncthreads();

        {   // H = relu(V@W1 + b1)
            const int c = t & (H - 1);
            const int r0 = (t >> 7) * 16;
            float acc[16];
#pragma unroll
            for (int i = 0; i < 16; ++i) acc[i] = 0.f;
            for (int k4 = 0; k4 < D / 4; ++k4) {
                float w0 = W1[(k4 * 4 + 0) * H + c];
                float w1 = W1[(k4 * 4 + 1) * H + c];
                float w2 = W1[(k4 * 4 + 2) * H + c];
                float w3 = W1[(k4 * 4 + 3) * H + c];
#pragma unroll
                for (int i = 0; i < 16; ++i) {
                    float4 v = *reinterpret_cast<const float4*>(&sV[r0 + i][k4 * 4]);
                    acc[i] = fmaf(v.w, w3, fmaf(v.z, w2, fmaf(v.y, w1, fmaf(v.x, w0, acc[i]))));
                }
            }
            float bb = b1[c];
#pragma unroll
            for (int i = 0; i < 16; ++i) {
                float h = acc[i] + bb;
                sH[r0 + i][c] = h > 0.f ? h : 0.f;
            }
        }
        __syncthreads();

        {   // P = H@W2 + b2 -> back into sV
            const int c = t;
            float acc[MLP_ROWS];
#pragma unroll
            for (int i = 0; i < MLP_ROWS; ++i) acc[i] = 0.f;
            for (int k4 = 0; k4 < H / 4; ++k4) {
                float w0 = W2[(k4 * 4 + 0) * D + c];
                float w1 = W2[(k4 * 4 + 1) * D + c];
                float w2 = W2[(k4 * 4 + 2) * D + c];
                float w3 = W2[(k4 * 4 + 3) * D + c];
#pragma unroll
                for (int i = 0; i < MLP_ROWS; ++i) {
                    float4 v = *reinterpret_cast<const float4*>(&sH[i][k4 * 4]);
                    acc[i] = fmaf(v.w, w3, fmaf(v.z, w2, fmaf(v.y, w1, fmaf(v.x, w0, acc[i]))));
                }
            }
            float bb = b2[c];
            __syncthreads();
#pragma unroll
            for (int i = 0; i < MLP_ROWS; ++i) sV[i][c] = acc[i] + bb;
        }
        __syncthreads();

        {   // row norms
            const int wave = t >> 6, lane = t & 63;
            for (int r = wave; r < MLP_ROWS; r += 4) {
                float s = 0.f;
#pragma unroll
                for (int c = 0; c < D / 64; ++c) {
                    float v = sV[r][lane + c * 64];
                    s = fmaf(v, v, s);
                }
#pragma unroll
                for (int off = 32; off > 0; off >>= 1) s += __shfl_down(s, off);
                if (lane == 0) sNrm[r] = s;
            }
        }
        __syncthreads();

        for (int i = t; i < MLP_ROWS * (D / 4); i += 256) {
            int r = i >> 6, c4 = i & 63;
            float scale = 1.0f / fmaxf(sqrtf(sNrm[r]), 1e-12f);
            ushort4 h, l;
            split_store(sV[r][c4 * 4 + 0] * scale, &h.x, &l.x);
            split_store(sV[r][c4 * 4 + 1] * scale, &h.y, &l.y);
            split_store(sV[r][c4 * 4 + 2] * scale, &h.z, &l.z);
            split_store(sV[r][c4 * 4 + 3] * scale, &h.w, &l.w);
            int grow = rowBase + r;
            size_t g = gidx(grow >> 7, c4 >> 3, (c4 >> 1) & 3, grow & 127) + (size_t)(c4 & 1) * 4;
            *reinterpret_cast<ushort4*>(&Ph[g]) = h;
            *reinterpret_cast<ushort4*>(&Pl[g]) = l;
        }
    } else {
        // ---------------- rownorm + zeroing branch ----------------
        const int rb = bid - 512;               // 0..255
        if (t < 128) keys[rb * 128 + t] = 0ULL; // zero 32768 keys total
        if (bid == 512) {
            if (t < 128) diagParts[t] = 0.f;
            if (t < 4) cnt[t] = 0;
        }
        const int wave = t >> 6, lane = t & 63;
#pragma unroll 1
        for (int i = 0; i < 16; ++i) {
            int gr = rb * 64 + wave * 16 + i;    // 0..16383
            const float* V = (gr < N) ? x : y;
            unsigned short* Vh = (gr < N) ? xh : yh;
            unsigned short* Vl = (gr < N) ? xl : yl;
            int row = gr & (N - 1);
            float4 v = *reinterpret_cast<const float4*>(&V[(size_t)row * D + lane * 4]);
            float s = fmaf(v.x, v.x, fmaf(v.y, v.y, fmaf(v.z, v.z, v.w * v.w)));
#pragma unroll
            for (int off = 32; off > 0; off >>= 1) s += __shfl_down(s, off);
            s = __shfl(s, 0);
            float scale = 1.0f / fmaxf(sqrtf(s), 1e-12f);
            ushort4 h, l;
            split_store(v.x * scale, &h.x, &l.x);
            split_store(v.y * scale, &h.y, &l.y);
            split_store(v.z * scale, &h.z, &l.z);
            split_store(v.w * scale, &h.w, &l.w);
            size_t g = gidx(row >> 7, lane >> 3, (lane >> 1) & 3, row & 127) + (size_t)(lane & 1) * 4;
            *reinterpret_cast<ushort4*>(&Vh[g]) = h;
            *reinterpret_cast<ushort4*>(&Vl[g]) = l;
        }
    }
}

// ---------------------------------------------------------------------------
// Kernel 2: both sims in one 8192-block launch (bit 12 selects sim_x/sim_y).
// Per sim: 128x128 tile, 4 waves (2x2 of 64x64). Per K-tile: stage Ah/Bh to
// LDS (16KB slot, 4 gloads/wave); al issued at loop top (arrives under hh),
// bl fenced below lh (sched_barrier) -> peak 12 live fragments (no spill).
// 48 MFMA/wave (hh, lh, hl). m97 2-barrier loop, 4 independent blocks/CU.
// ---------------------------------------------------------------------------
__global__ __launch_bounds__(256, 4) void sim_argmax_mfma(
    const unsigned short* __restrict__ Axh, const unsigned short* __restrict__ Axl,
    const unsigned short* __restrict__ Byh, const unsigned short* __restrict__ Byl,
    const unsigned short* __restrict__ Ayh, const unsigned short* __restrict__ Ayl,
    const unsigned short* __restrict__ Bxh, const unsigned short* __restrict__ Bxl,
    ull* __restrict__ keys, float* __restrict__ diagParts)
{
    __shared__ s16x8 sS[2][512];      // 16 KB single slot: [Ah,Bh][kq*128+m]
    __shared__ ull kbufR[128][2];     // 2 KB
    __shared__ ull kbufC[128][2];     // 2 KB
    __shared__ float sDiag[4];

    const int t = threadIdx.x;
    const int w = t >> 6, lane = t & 63;
    const int wr = w >> 1, wc = w & 1;   // 2x2 wave grid, each 64x64

    const int bidFull = blockIdx.x;
    const int sim = bidFull >> 12;                    // 0: pxn@yn^T, 1: pyn@xn^T
    const int bid = bidFull & 4095;

    const unsigned short* Ah = sim ? Ayh : Axh;
    const unsigned short* Al = sim ? Ayl : Axl;
    const unsigned short* Bh = sim ? Bxh : Byh;
    const unsigned short* Bl = sim ? Bxl : Byl;
    ull* rowKeys = keys + (sim ? 2 * N : 0);
    ull* colKeys = keys + (sim ? 3 * N : (size_t)N);
    float* diagP = diagParts + (sim ? 64 : 0);

    // 2D XCD swizzle: 4096 tiles/sim = 64x64; XCD k owns
    // rowTiles [(k&3)*16,+16) x colTiles [(k>>2)*32,+32); row fastest.
    const int xcd = bid & 7, local = bid >> 3;        // local 0..511
    const int rowTile = (xcd & 3) * 16 + (local & 15);
    const int colTile = (xcd >> 2) * 32 + (local >> 4);
    const int rowBase = rowTile * 128;
    const int colBase = colTile * 128;

    fp32x4 acc[4][4];
#pragma unroll
    for (int i = 0; i < 4; ++i)
#pragma unroll
        for (int j = 0; j < 4; ++j) acc[i][j] = (fp32x4){0.f, 0.f, 0.f, 0.f};

    // per-plane granule bases for this block (ushort units)
    const unsigned short* pAh = Ah + (size_t)rowTile * 4096 * 8;
    const unsigned short* pBh = Bh + (size_t)colTile * 4096 * 8;

    // direct-load per-wave fragment bases for the low planes
    const int fOff = (lane >> 4) * 128 + (lane & 15);
    const unsigned short* aL = Al + ((size_t)rowTile * 4096 + fOff + wr * 64) * 8;
    const unsigned short* bL = Bl + ((size_t)colTile * 4096 + fOff + wc * 64) * 8;

#define FRAG(base, kt, f) (*reinterpret_cast<const s16x8*>((base) + ((size_t)(kt) * 512 + (f) * 16) * 8))

    // stage K-tile kt: wave w covers kq=w of Ah,Bh -> 4 x 1KB gload16.
#define STAGE(kt)                                                               \
    do {                                                                        \
        const size_t o0 = (size_t)(kt) * 512 + w * 128 + lane;                  \
        const size_t o1 = o0 + 64;                                              \
        gload16(pAh + o0 * 8, (void*)&sS[0][w * 128]);                          \
        gload16(pAh + o1 * 8, (void*)&sS[0][w * 128 + 64]);                     \
        gload16(pBh + o0 * 8, (void*)&sS[1][w * 128]);                          \
        gload16(pBh + o1 * 8, (void*)&sS[1][w * 128 + 64]);                     \
    } while (0)

    STAGE(0);

    const int aBase = fOff + wr * 64;
    const int bBase = fOff + wc * 64;

#pragma unroll 1
    for (int kt = 0; kt < 8; ++kt) {
        __syncthreads();   // syncA: STAGE(kt) landed for all waves (vmcnt(0))

        // issue al early: arrives under the hh cluster (consumed in lh)
        s16x8 al[4];
#pragma unroll
        for (int f = 0; f < 4; ++f) al[f] = FRAG(aL, kt, f);

        s16x8 ah[4], bh[4];
#pragma unroll
        for (int f = 0; f < 4; ++f) ah[f] = sS[0][aBase + f * 16];
#pragma unroll
        for (int f = 0; f < 4; ++f) bh[f] = sS[1][bBase + f * 16];

        __builtin_amdgcn_s_setprio(1);
#pragma unroll
        for (int fm = 0; fm < 4; ++fm)
#pragma unroll
            for (int fn = 0; fn < 4; ++fn)
                acc[fm][fn] = __builtin_amdgcn_mfma_f32_16x16x32_bf16(ah[fm], bh[fn], acc[fm][fn], 0, 0, 0);
        __builtin_amdgcn_s_setprio(0);

        __builtin_amdgcn_s_setprio(1);
#pragma unroll
        for (int fm = 0; fm < 4; ++fm)
#pragma unroll
            for (int fn = 0; fn < 4; ++fn)
                acc[fm][fn] = __builtin_amdgcn_mfma_f32_16x16x32_bf16(al[fm], bh[fn], acc[fm][fn], 0, 0, 0);
        __builtin_amdgcn_s_setprio(0);

        // fence: keep bl loads BELOW lh so peak liveness stays at 12 frags
        __builtin_amdgcn_sched_barrier(0);

        {   // high-A x low-B: bl fetched direct; stall cross-block hidden
            s16x8 bl[4];
#pragma unroll
            for (int f = 0; f < 4; ++f) bl[f] = FRAG(bL, kt, f);
            __builtin_amdgcn_s_setprio(1);
#pragma unroll
            for (int fm = 0; fm < 4; ++fm)
#pragma unroll
                for (int fn = 0; fn < 4; ++fn)
                    acc[fm][fn] = __builtin_amdgcn_mfma_f32_16x16x32_bf16(ah[fm], bl[fn], acc[fm][fn], 0, 0, 0);
            __builtin_amdgcn_s_setprio(0);
        }

        __syncthreads();               // syncB: all waves done reading the slot
        if (kt < 7) STAGE(kt + 1);     // overwrite; next syncA waits it
    }
#undef STAGE
#undef FRAG

    const int R0 = wr * 64;
    const int C0 = wc * 64;

    // ---- diagonal (loss) partial ----
    if (rowTile == colTile) {
        float s = 0.f;
        if (wr == wc) {
            int dr = (lane & 15) - (lane >> 4) * 4;
            if (dr >= 0 && dr < 4) {
#pragma unroll
                for (int fm = 0; fm < 4; ++fm) s += acc[fm][fm][dr];
            }
        }
#pragma unroll
        for (int off = 32; off > 0; off >>= 1) s += __shfl_down(s, off);
        if (lane == 0) sDiag[w] = s;
        __syncthreads();
        if (t == 0) diagP[rowTile] = ((sDiag[0] + sDiag[1]) + sDiag[2]) + sDiag[3];
    }

    // ---- row argmax candidates (value-first); C/D: col=lane&15, row=(lane>>4)*4+r
#pragma unroll
    for (int fm = 0; fm < 4; ++fm) {
#pragma unroll
        for (int r = 0; r < 4; ++r) {
            int rowLoc = R0 + fm * 16 + (lane >> 4) * 4 + r;
            float m = fmaxf(fmaxf(acc[fm][0][r], acc[fm][1][r]), fmaxf(acc[fm][2][r], acc[fm][3][r]));
#pragma unroll
            for (int off = 1; off < 16; off <<= 1) m = fmaxf(m, __shfl_xor(m, off));
            unsigned idx = 0xFFFFFFFFu;
#pragma unroll
            for (int fn = 0; fn < 4; ++fn) {
                unsigned gcol = (unsigned)(colBase + C0 + fn * 16 + (lane & 15));
                if (acc[fm][fn][r] == m && gcol < idx) idx = gcol;
            }
#pragma unroll
            for (int off = 1; off < 16; off <<= 1) {
                unsigned o = __shfl_xor(idx, off);
                if (o < idx) idx = o;
            }
            if ((lane & 15) == 0)
                kbufR[rowLoc][wc] = ((ull)f2ord(m) << 32) | (unsigned)(~idx);
        }
    }

    // ---- col argmax candidates ----
#pragma unroll
    for (int fn = 0; fn < 4; ++fn) {
        int colLoc = C0 + fn * 16 + (lane & 15);
        float m = -3.4e38f;
#pragma unroll
        for (int fm = 0; fm < 4; ++fm) {
            float m01 = fmaxf(acc[fm][fn][0], acc[fm][fn][1]);
            float m23 = fmaxf(acc[fm][fn][2], acc[fm][fn][3]);
            m = fmaxf(m, fmaxf(m01, m23));
        }
        m = fmaxf(m, __shfl_xor(m, 16));
        m = fmaxf(m, __shfl_xor(m, 32));
        unsigned idx = 0xFFFFFFFFu;
#pragma unroll
        for (int fm = 0; fm < 4; ++fm) {
#pragma unroll
            for (int r = 0; r < 4; ++r) {
                unsigned grow = (unsigned)(rowBase + R0 + fm * 16 + (lane >> 4) * 4 + r);
                if (acc[fm][fn][r] == m && grow < idx) idx = grow;
            }
        }
        {
            unsigned o = __shfl_xor(idx, 16);
            if (o < idx) idx = o;
            o = __shfl_xor(idx, 32);
            if (o < idx) idx = o;
        }
        if ((lane >> 4) == 0)
            kbufC[colLoc][wr] = ((ull)f2ord(m) << 32) | (unsigned)(~idx);
    }

    __syncthreads();

    // ---- one global atomic per row / col ----
    if (t < 128) {
        ull best = umax64(kbufR[t][0], kbufR[t][1]);
        atomicMax(&rowKeys[rowBase + t], best);
    } else {
        int c = t - 128;
        ull best = umax64(kbufC[c][0], kbufC[c][1]);
        atomicMax(&colKeys[colBase + c], best);
    }
}

// ---------------------------------------------------------------------------
// Kernel 3: parallel deterministic counts (int atomics).
// ---------------------------------------------------------------------------
__global__ __launch_bounds__(256) void count_kernel(const ull* __restrict__ keys, int* __restrict__ cnt)
{
    const int t = threadIdx.x;
    const int i = blockIdx.x * 256 + t;
    const int lane = t & 63;
#pragma unroll
    for (int a = 0; a < 4; ++a) {
        int s = ((~(unsigned)keys[a * N + i]) == (unsigned)i);
#pragma unroll
        for (int off = 32; off > 0; off >>= 1) s += __shfl_down(s, off);
        if (lane == 0) atomicAdd(&cnt[a], s);
    }
}

// ---------------------------------------------------------------------------
// Kernel 4: final scalars.
// ---------------------------------------------------------------------------
__global__ __launch_bounds__(64) void final_kernel(
    const float* __restrict__ diagParts, const int* __restrict__ cnt, float* __restrict__ out)
{
    const int lane = threadIdx.x;
    double vx = (double)diagParts[lane];
    double vy = (double)diagParts[64 + lane];
#pragma unroll
    for (int off = 32; off > 0; off >>= 1) {
        vx += __shfl_down(vx, off);
        vy += __shfl_down(vy, off);
    }
    if (lane == 0) {
        float invN = 1.0f / (float)N;
        out[0] = (float)(-0.5 * (vx + vy) / (double)N);
        out[1] = 0.5f * ((float)cnt[1] * invN) + (float)cnt[0] * invN;
        out[2] = 0.5f * ((float)cnt[3] * invN) + (float)cnt[2] * invN;
    }
}

// ---------------------------------------------------------------------------
extern "C" void kernel_launch(void* const* d_in, const int* in_sizes, int n_in,
                              void* d_out, int out_size, void* d_ws, size_t ws_size,
                              hipStream_t stream)
{
    (void)in_sizes; (void)n_in; (void)out_size; (void)ws_size;
    const float* x  = (const float*)d_in[0];
    const float* y  = (const float*)d_in[1];
    const float* W1 = (const float*)d_in[2];
    const float* b1 = (const float*)d_in[3];
    const float* W2 = (const float*)d_in[4];
    const float* b2 = (const float*)d_in[5];
    float* out = (float*)d_out;

    const size_t ND = (size_t)N * D;
    unsigned short* pxh = (unsigned short*)d_ws;   // 8 bf16 planes x 4 MB = 32 MB
    unsigned short* pxl = pxh + ND;
    unsigned short* pyh = pxl + ND;
    unsigned short* pyl = pyh + ND;
    unsigned short* xh  = pyl + ND;
    unsigned short* xl  = xh + ND;
    unsigned short* yh  = xl + ND;
    unsigned short* yl  = yh + ND;
    ull* keys = (ull*)(yl + ND);                   // 256 KB
    float* diagParts = (float*)(keys + 4 * N);     // 128 floats
    int* cnt = (int*)(diagParts + 128);            // 4 ints

    prep_kernel<<<768, 256, 0, stream>>>(x, y, W1, b1, W2, b2,
                                         pxh, pxl, pyh, pyl, xh, xl, yh, yl,
                                         keys, cnt, diagParts);

    sim_argmax_mfma<<<8192, 256, 0, stream>>>(pxh, pxl, yh, yl,
                                              pyh, pyl, xh, xl,
                                              keys, diagParts);

    count_kernel<<<32, 256, 0, stream>>>(keys, cnt);
    final_kernel<<<1, 64, 0, stream>>>(diagParts, cnt, out);
}